// Round 4
// baseline (102.666 us; speedup 1.0000x reference)
//
#include <hip/hip_runtime.h>
#include <hip/hip_bf16.h>

#define BATCH    8192
#define NF       39      // num_fields
#define ED       64      // embed dim
#define RANK     32
#define SPW      2       // samples per wave
#define KST      72      // LDS k-stride in halves: 144 B = 36 dwords; 36/4=9 odd
                         // -> 8 consecutive lanes hit 8 distinct b128 bank-groups

typedef _Float16 half8  __attribute__((ext_vector_type(8)));
typedef float    f32x16 __attribute__((ext_vector_type(16)));

// One wave = 2 samples, wave-private LDS slice, no block barriers.
// W frags (15 x half8 = 60 VGPR) built once per wave, register-resident.
// Per sample: 39 coalesced row-gathers -> f16 pack -> LDS [i][k] ->
// per 32-col tile: 3 B-frags; phase W0 (2 acc, 6 MFMA) folded to scalar,
// regs reused for phase W1 (3 acc, 9 MFMA). C/D layout irrelevant: tiles
// never straddle samples and we sum every element.
__global__ __launch_bounds__(256, 3) void tfm_kernel(
    const int*   __restrict__ x,        // (B, NF)
    const float* __restrict__ embed,    // (100000, ED)
    const float* __restrict__ linw,     // (100000, 1)
    const float* __restrict__ lbias,    // (1,)
    const float* __restrict__ W0,       // (2, RANK, NF)
    const float* __restrict__ W1,       // (3, RANK, NF)
    float*       __restrict__ out)      // (B,)
{
    __shared__ __align__(16) _Float16 Es[4][ED][KST];   // 36864 B

    const int t    = threadIdx.x;
    const int lane = t & 63;
    const int w    = t >> 6;
    const int s0   = (blockIdx.x * 4 + w) * SPW;

    const float bias = lbias[0];
    const int j  = lane & 31;   // rank row for W frags / col-in-tile for B
    const int kh = lane >> 5;   // k-half selector

    // ---- x vectors + linear gathers issued up front ----
    int xv[SPW];
#pragma unroll
    for (int si = 0; si < SPW; ++si)
        xv[si] = (lane < NF) ? x[(s0 + si) * NF + lane] : 0;

    float lv[SPW];
#pragma unroll
    for (int si = 0; si < SPW; ++si)
        lv[si] = (lane < NF) ? linw[xv[si]] : 0.0f;

    // ---- W fragments, register-resident (15 x half8 = 60 VGPR) ----
    // A-frag map: row j = lane&31, k = kc*16 + kh*8 + e  (same k-map as B reads)
    half8 wf[5][3];
#pragma unroll
    for (int l = 0; l < 5; ++l) {
        const float* base = (l < 2) ? (W0 + (l * RANK + j) * NF)
                                    : (W1 + ((l - 2) * RANK + j) * NF);
#pragma unroll
        for (int kc = 0; kc < 3; ++kc)
#pragma unroll
            for (int e = 0; e < 8; ++e) {
                int k = kc * 16 + kh * 8 + e;
                wf[l][kc][e] = (k < NF) ? (_Float16)base[k] : (_Float16)0.0f;
            }
    }

#pragma unroll
    for (int si = 0; si < SPW; ++si) {
        // ---- gather 39 rows; each instr loads one full 256B row (lane=col) ----
        float r[NF];
#pragma unroll
        for (int k = 0; k < NF; ++k) {
            int xi = __builtin_amdgcn_readlane(xv[si], k);  // uniform -> SGPR base
            r[k] = embed[(size_t)xi * ED + lane];
        }

        // ---- pack f16 along k (free transpose: lane = column), 6 x b128 ----
#pragma unroll
        for (int c6 = 0; c6 < 6; ++c6) {
            half8 hh;
#pragma unroll
            for (int e = 0; e < 8; ++e) {
                int k = c6 * 8 + e;
                hh[e] = (k < NF) ? (_Float16)r[k] : (_Float16)0.0f;
            }
            *(half8*)&Es[w][lane][c6 * 8] = hh;
        }
        // same-wave LDS: compiler's lgkmcnt dependency ordering suffices

        float ssum = lv[si];

#pragma unroll
        for (int tile = 0; tile < 2; ++tile) {
            const int c = tile * 32 + j;
            half8 bf[3];
#pragma unroll
            for (int kc = 0; kc < 3; ++kc)
                bf[kc] = *(const half8*)&Es[w][c][kc * 16 + kh * 8];

            // ---- phase W0: 2 accumulators, fold immediately ----
            {
                f32x16 a0, a1;
#pragma unroll
                for (int e = 0; e < 16; ++e) { a0[e] = 0.0f; a1[e] = 0.0f; }
#pragma unroll
                for (int kc = 0; kc < 3; ++kc) {
                    a0 = __builtin_amdgcn_mfma_f32_32x32x16_f16(wf[0][kc], bf[kc], a0, 0, 0, 0);
                    a1 = __builtin_amdgcn_mfma_f32_32x32x16_f16(wf[1][kc], bf[kc], a1, 0, 0, 0);
                }
#pragma unroll
                for (int e = 0; e < 16; ++e) ssum += a0[e] * a1[e];
            }
            // ---- phase W1: 3 accumulators (reuses W0's registers) ----
            {
                f32x16 c0, c1, c2;
#pragma unroll
                for (int e = 0; e < 16; ++e) { c0[e] = 0.0f; c1[e] = 0.0f; c2[e] = 0.0f; }
#pragma unroll
                for (int kc = 0; kc < 3; ++kc) {
                    c0 = __builtin_amdgcn_mfma_f32_32x32x16_f16(wf[2][kc], bf[kc], c0, 0, 0, 0);
                    c1 = __builtin_amdgcn_mfma_f32_32x32x16_f16(wf[3][kc], bf[kc], c1, 0, 0, 0);
                    c2 = __builtin_amdgcn_mfma_f32_32x32x16_f16(wf[4][kc], bf[kc], c2, 0, 0, 0);
                }
#pragma unroll
                for (int e = 0; e < 16; ++e) ssum += c0[e] * c1[e] * c2[e];
            }
        }

        // ---- 64-lane reduce, lane 0 writes ----
#pragma unroll
        for (int off = 32; off > 0; off >>= 1) ssum += __shfl_down(ssum, off, 64);
        if (lane == 0) out[s0 + si] = ssum + bias;
    }
}

extern "C" void kernel_launch(void* const* d_in, const int* in_sizes, int n_in,
                              void* d_out, int out_size, void* d_ws, size_t ws_size,
                              hipStream_t stream) {
    const int*   x     = (const int*)  d_in[0];
    const float* embed = (const float*)d_in[1];
    const float* linw  = (const float*)d_in[2];
    const float* lbias = (const float*)d_in[3];
    const float* W0    = (const float*)d_in[4];
    const float* W1    = (const float*)d_in[5];
    float*       out   = (float*)d_out;

    // 1024 blocks x 4 waves x 2 samples = 8192
    tfm_kernel<<<BATCH / (4 * SPW), 256, 0, stream>>>(x, embed, linw, lbias, W0, W1, out);
}

// Round 5
// 99.201 us; speedup vs baseline: 1.0349x; 1.0349x over previous
//
#include <hip/hip_runtime.h>
#include <hip/hip_bf16.h>

#define BATCH    8192
#define NF       39      // num_fields
#define ED       64      // embed dim
#define RANK     32
#define SPW      2       // samples per wave
#define KST      48      // LDS k-stride in halves (96 B rows, 16B-aligned)
#define NFRAG    15      // 5 l-slices x 3 k-chunks

typedef _Float16 half8  __attribute__((ext_vector_type(8)));
typedef float    f32x16 __attribute__((ext_vector_type(16)));

// ---- prep: build the 15 W A-fragments in per-lane MFMA layout ----
// wsW[(l*3+kc)*64 + lane] = half8 of W[l-slice] row j=lane&31,
// k = kc*16 + (lane>>5)*8 + e  (k>=39 zero-padded).
// Main kernel then loads W with 15 fully-coalesced dwordx4.
__global__ void prep_w(const float* __restrict__ W0,
                       const float* __restrict__ W1,
                       half8* __restrict__ wsW) {
    int d = blockIdx.x * 256 + threadIdx.x;
    if (d >= NFRAG * 64) return;
    int fid  = d >> 6;          // l*3 + kc
    int lane = d & 63;
    int l = fid / 3, kc = fid % 3;
    int j = lane & 31, kh = lane >> 5;
    const float* base = (l < 2) ? (W0 + (l * RANK + j) * NF)
                                : (W1 + ((l - 2) * RANK + j) * NF);
    half8 h;
#pragma unroll
    for (int e = 0; e < 8; ++e) {
        int k = kc * 16 + kh * 8 + e;
        h[e] = (k < NF) ? (_Float16)base[k] : (_Float16)0.0f;
    }
    wsW[d] = h;
}

// ---- main: one wave = 2 samples, wave+sample-private LDS, no barriers ----
__global__ __launch_bounds__(256, 3) void tfm_kernel(
    const int*   __restrict__ x,        // (B, NF)
    const float* __restrict__ embed,    // (100000, ED)
    const float* __restrict__ linw,     // (100000, 1)
    const float* __restrict__ lbias,    // (1,)
    const half8* __restrict__ wsW,      // [NFRAG][64]
    float*       __restrict__ out)      // (B,)
{
    __shared__ __align__(16) _Float16 Es[4][SPW][ED][KST];   // 49152 B

    const int t    = threadIdx.x;
    const int lane = t & 63;
    const int w    = t >> 6;
    const int s0   = (blockIdx.x * 4 + w) * SPW;

    const float bias = lbias[0];
    const int j  = lane & 31;
    const int kh = lane >> 5;

    // ---- x vectors + linear gathers ----
    int xv[SPW];
#pragma unroll
    for (int si = 0; si < SPW; ++si)
        xv[si] = (lane < NF) ? x[(s0 + si) * NF + lane] : 0;

    float lv[SPW];
#pragma unroll
    for (int si = 0; si < SPW; ++si)
        lv[si] = (lane < NF) ? linw[xv[si]] : 0.0f;

    // ---- W fragments: 15 coalesced dwordx4 loads ----
    half8 wf[5][3];
#pragma unroll
    for (int l = 0; l < 5; ++l)
#pragma unroll
        for (int kc = 0; kc < 3; ++kc)
            wf[l][kc] = wsW[(l * 3 + kc) * 64 + lane];

    // ---- gather BOTH samples' rows first (pipelined latency) ----
    float r[SPW][NF];
#pragma unroll
    for (int si = 0; si < SPW; ++si)
#pragma unroll
        for (int k = 0; k < NF; ++k) {
            int xi = __builtin_amdgcn_readlane(xv[si], k);  // uniform -> SGPR base
            r[si][k] = embed[(size_t)xi * ED + lane];
        }

    // ---- pack f16 along k (lane = embed column), 6 x b128 per sample ----
#pragma unroll
    for (int si = 0; si < SPW; ++si)
#pragma unroll
        for (int c6 = 0; c6 < 6; ++c6) {
            half8 hh;
#pragma unroll
            for (int e = 0; e < 8; ++e) {
                int k = c6 * 8 + e;
                hh[e] = (k < NF) ? (_Float16)r[si][k] : (_Float16)0.0f;
            }
            *(half8*)&Es[w][si][lane][c6 * 8] = hh;
        }
    // same-wave LDS: compiler's lgkmcnt dependency ordering suffices

#pragma unroll
    for (int si = 0; si < SPW; ++si) {
        float ssum = lv[si];

#pragma unroll
        for (int tile = 0; tile < 2; ++tile) {
            const int c = tile * 32 + j;
            half8 bf[3];
#pragma unroll
            for (int kc = 0; kc < 3; ++kc)
                bf[kc] = *(const half8*)&Es[w][si][c][kc * 16 + kh * 8];

            // phase W0: 2 accumulators, folded immediately
            {
                f32x16 a0, a1;
#pragma unroll
                for (int e = 0; e < 16; ++e) { a0[e] = 0.0f; a1[e] = 0.0f; }
#pragma unroll
                for (int kc = 0; kc < 3; ++kc) {
                    a0 = __builtin_amdgcn_mfma_f32_32x32x16_f16(wf[0][kc], bf[kc], a0, 0, 0, 0);
                    a1 = __builtin_amdgcn_mfma_f32_32x32x16_f16(wf[1][kc], bf[kc], a1, 0, 0, 0);
                }
#pragma unroll
                for (int e = 0; e < 16; ++e) ssum += a0[e] * a1[e];
            }
            // phase W1: 3 accumulators (reuses W0's registers)
            {
                f32x16 c0, c1, c2;
#pragma unroll
                for (int e = 0; e < 16; ++e) { c0[e] = 0.0f; c1[e] = 0.0f; c2[e] = 0.0f; }
#pragma unroll
                for (int kc = 0; kc < 3; ++kc) {
                    c0 = __builtin_amdgcn_mfma_f32_32x32x16_f16(wf[2][kc], bf[kc], c0, 0, 0, 0);
                    c1 = __builtin_amdgcn_mfma_f32_32x32x16_f16(wf[3][kc], bf[kc], c1, 0, 0, 0);
                    c2 = __builtin_amdgcn_mfma_f32_32x32x16_f16(wf[4][kc], bf[kc], c2, 0, 0, 0);
                }
#pragma unroll
                for (int e = 0; e < 16; ++e) ssum += c0[e] * c1[e] * c2[e];
            }
        }

#pragma unroll
        for (int off = 32; off > 0; off >>= 1) ssum += __shfl_down(ssum, off, 64);
        if (lane == 0) out[s0 + si] = ssum + bias;
    }
}

extern "C" void kernel_launch(void* const* d_in, const int* in_sizes, int n_in,
                              void* d_out, int out_size, void* d_ws, size_t ws_size,
                              hipStream_t stream) {
    const int*   x     = (const int*)  d_in[0];
    const float* embed = (const float*)d_in[1];
    const float* linw  = (const float*)d_in[2];
    const float* lbias = (const float*)d_in[3];
    const float* W0    = (const float*)d_in[4];
    const float* W1    = (const float*)d_in[5];
    float*       out   = (float*)d_out;
    half8*       wsW   = (half8*)d_ws;          // 15*64*16 B = 15360 B

    prep_w<<<(NFRAG * 64 + 255) / 256, 256, 0, stream>>>(W0, W1, wsW);
    // 1024 blocks x 4 waves x 2 samples = 8192
    tfm_kernel<<<BATCH / (4 * SPW), 256, 0, stream>>>(x, embed, linw, lbias, wsW, out);
}

// Round 6
// 94.978 us; speedup vs baseline: 1.0810x; 1.0445x over previous
//
#include <hip/hip_runtime.h>
#include <hip/hip_bf16.h>

#define BATCH    8192
#define NF       39      // num_fields
#define ED       64      // embed dim
#define RANK     32
#define KST      72      // f16 LDS k-stride in halves (144 B): lanes 0..7 -> banks 0,4,..,28: conflict-free b128
#define NFRAG    15      // 5 l-slices x 3 k-chunks

typedef _Float16 half8  __attribute__((ext_vector_type(8)));
typedef float    f32x16 __attribute__((ext_vector_type(16)));

// ---- prep: build the 15 W A-fragments in per-lane MFMA layout ----
// wsW[(l*3+kc)*64 + lane] = half8 of W row j=lane&31, k = kc*16 + (lane>>5)*8 + e.
__global__ void prep_w(const float* __restrict__ W0,
                       const float* __restrict__ W1,
                       half8* __restrict__ wsW) {
    int d = blockIdx.x * 256 + threadIdx.x;
    if (d >= NFRAG * 64) return;
    int fid  = d >> 6;
    int lane = d & 63;
    int l = fid / 3, kc = fid % 3;
    int j = lane & 31, kh = lane >> 5;
    const float* base = (l < 2) ? (W0 + (l * RANK + j) * NF)
                                : (W1 + ((l - 2) * RANK + j) * NF);
    half8 h;
#pragma unroll
    for (int e = 0; e < 8; ++e) {
        int k = kc * 16 + kh * 8 + e;
        h[e] = (k < NF) ? (_Float16)base[k] : (_Float16)0.0f;
    }
    wsW[d] = h;
}

// ---- main: one wave = one sample. W frags in LDS (block-staged once). ----
// Gather 39 rows into 39 dest VGPRs (fully pipelined - this is the whole point),
// pack f16 -> wave-private LDS [i][k], B-frags via ds_read_b128, A-frags from LDS.
__global__ __launch_bounds__(256, 3) void tfm_kernel(
    const int*   __restrict__ x,        // (B, NF)
    const float* __restrict__ embed,    // (100000, ED)
    const float* __restrict__ linw,     // (100000, 1)
    const float* __restrict__ lbias,    // (1,)
    const half8* __restrict__ wsW,      // [NFRAG][64]
    float*       __restrict__ out)      // (B,)
{
    __shared__ __align__(16) _Float16 Ws[NFRAG * 64 * 8];   // 15360 B
    __shared__ __align__(16) _Float16 Ef[4][ED][KST];       // 36864 B

    const int t    = threadIdx.x;
    const int lane = t & 63;
    const int w    = t >> 6;
    const int s    = blockIdx.x * 4 + w;     // one sample per wave

    const int j  = lane & 31;
    const int kh = lane >> 5;

    // ---- issue the gather chain first ----
    const int xi_v = (lane < NF) ? x[s * NF + lane] : 0;
    const float lv = (lane < NF) ? linw[xi_v] : 0.0f;

    float r[NF];
#pragma unroll
    for (int k = 0; k < NF; ++k) {
        int xi = __builtin_amdgcn_readlane(xi_v, k);   // uniform -> SGPR base
        r[k] = embed[(size_t)xi * ED + lane];          // coalesced 256B row
    }

    // ---- stage W frags into LDS (independent loads, overlap the gather) ----
    {
        const uint4* src = (const uint4*)wsW;
        uint4*       dst = (uint4*)Ws;
#pragma unroll
        for (int i = 0; i < NFRAG * 64 / 256; ++i)      // 960/256: 3 full passes
            dst[i * 256 + t] = src[i * 256 + t];
        if (t < NFRAG * 64 - 768) dst[768 + t] = src[768 + t];
    }

    const float bias = lbias[0];

    // ---- pack f16 along k (lane = embed column), 6 x b128, wave-private ----
#pragma unroll
    for (int c6 = 0; c6 < 6; ++c6) {
        half8 hh;
#pragma unroll
        for (int e = 0; e < 8; ++e) {
            int k = c6 * 8 + e;
            hh[e] = (k < NF) ? (_Float16)r[k] : (_Float16)0.0f;
        }
        *(half8*)&Ef[w][lane][c6 * 8] = hh;
    }

    __syncthreads();   // Ws visible to all waves (Ef is wave-private anyway)

    const half8* Wf = (const half8*)Ws;
    float ssum = lv;

#pragma unroll
    for (int tile = 0; tile < 2; ++tile) {
        const int c = tile * 32 + j;
        half8 bf[3];
#pragma unroll
        for (int kc = 0; kc < 3; ++kc)
            bf[kc] = *(const half8*)&Ef[w][c][kc * 16 + kh * 8];

        // phase W0: 2 accumulators, folded immediately
        {
            f32x16 a0, a1;
#pragma unroll
            for (int e = 0; e < 16; ++e) { a0[e] = 0.0f; a1[e] = 0.0f; }
#pragma unroll
            for (int kc = 0; kc < 3; ++kc) {
                a0 = __builtin_amdgcn_mfma_f32_32x32x16_f16(Wf[(0 * 3 + kc) * 64 + lane], bf[kc], a0, 0, 0, 0);
                a1 = __builtin_amdgcn_mfma_f32_32x32x16_f16(Wf[(1 * 3 + kc) * 64 + lane], bf[kc], a1, 0, 0, 0);
            }
#pragma unroll
            for (int e = 0; e < 16; ++e) ssum += a0[e] * a1[e];
        }
        // phase W1: 3 accumulators (reuses W0's registers)
        {
            f32x16 c0, c1, c2;
#pragma unroll
            for (int e = 0; e < 16; ++e) { c0[e] = 0.0f; c1[e] = 0.0f; c2[e] = 0.0f; }
#pragma unroll
            for (int kc = 0; kc < 3; ++kc) {
                c0 = __builtin_amdgcn_mfma_f32_32x32x16_f16(Wf[(2 * 3 + kc) * 64 + lane], bf[kc], c0, 0, 0, 0);
                c1 = __builtin_amdgcn_mfma_f32_32x32x16_f16(Wf[(3 * 3 + kc) * 64 + lane], bf[kc], c1, 0, 0, 0);
                c2 = __builtin_amdgcn_mfma_f32_32x32x16_f16(Wf[(4 * 3 + kc) * 64 + lane], bf[kc], c2, 0, 0, 0);
            }
#pragma unroll
            for (int e = 0; e < 16; ++e) ssum += c0[e] * c1[e] * c2[e];
        }
    }

    // ---- 64-lane reduce, lane 0 writes ----
#pragma unroll
    for (int off = 32; off > 0; off >>= 1) ssum += __shfl_down(ssum, off, 64);
    if (lane == 0) out[s] = ssum + bias;
}

extern "C" void kernel_launch(void* const* d_in, const int* in_sizes, int n_in,
                              void* d_out, int out_size, void* d_ws, size_t ws_size,
                              hipStream_t stream) {
    const int*   x     = (const int*)  d_in[0];
    const float* embed = (const float*)d_in[1];
    const float* linw  = (const float*)d_in[2];
    const float* lbias = (const float*)d_in[3];
    const float* W0    = (const float*)d_in[4];
    const float* W1    = (const float*)d_in[5];
    float*       out   = (float*)d_out;
    half8*       wsW   = (half8*)d_ws;          // 15*64*16 B = 15360 B

    prep_w<<<(NFRAG * 64 + 255) / 256, 256, 0, stream>>>(W0, W1, wsW);
    // 2048 blocks x 4 waves x 1 sample = 8192
    tfm_kernel<<<BATCH / 4, 256, 0, stream>>>(x, embed, linw, lbias, wsW, out);
}